// Round 1
// baseline (6936.568 us; speedup 1.0000x reference)
//
#include <hip/hip_runtime.h>

#define NN 100000
#define EE 1600000
#define ENN (EE + NN)
#define DIN 256
#define DH 128
#define PH 512

static constexpr float BN_EPS_C = 1e-5f;

// ---------------- graph build ----------------

__global__ void init_deg_k(int* __restrict__ deg1, int* __restrict__ deg2) {
    int i = blockIdx.x * 256 + threadIdx.x;
    if (i < NN) { deg1[i] = 1; deg2[i] = 1; }  // self-loop counted here
}

__global__ void count_deg_k(const int* __restrict__ dst, int* __restrict__ deg) {
    int e = blockIdx.x * 256 + threadIdx.x;
    if (e < EE) atomicAdd(&deg[dst[e]], 1);
}

__global__ void dinv_k(const int* __restrict__ deg, float* __restrict__ dinv) {
    int i = blockIdx.x * 256 + threadIdx.x;
    if (i < NN) dinv[i] = rsqrtf((float)deg[i]);
}

// exclusive scan of deg[NN] -> rowoff[NN+1]; chunk = 1024/block
__global__ void scan1_k(const int* __restrict__ deg, int* __restrict__ bsum) {
    __shared__ int sh[256];
    int t = threadIdx.x;
    int base = blockIdx.x * 1024 + t * 4;
    int s = 0;
#pragma unroll
    for (int i = 0; i < 4; i++) { int idx = base + i; if (idx < NN) s += deg[idx]; }
    sh[t] = s; __syncthreads();
    for (int off = 128; off > 0; off >>= 1) { if (t < off) sh[t] += sh[t + off]; __syncthreads(); }
    if (t == 0) bsum[blockIdx.x] = sh[0];
}

__global__ void scan2_k(int* __restrict__ bsum, int nb) {
    __shared__ int sh[128];
    int t = threadIdx.x;
    int my = (t < nb) ? bsum[t] : 0;
    sh[t] = my; __syncthreads();
    for (int off = 1; off < 128; off <<= 1) {
        int v = (t >= off) ? sh[t - off] : 0;
        __syncthreads(); sh[t] += v; __syncthreads();
    }
    if (t < nb) bsum[t] = sh[t] - my;  // exclusive
}

__global__ void scan3_k(const int* __restrict__ deg, const int* __restrict__ bsum,
                        int* __restrict__ rowoff) {
    __shared__ int sh[256];
    int t = threadIdx.x;
    int base = blockIdx.x * 1024 + t * 4;
    int v[4]; int s = 0;
#pragma unroll
    for (int i = 0; i < 4; i++) { int idx = base + i; v[i] = (idx < NN) ? deg[idx] : 0; s += v[i]; }
    int my = s;
    sh[t] = s; __syncthreads();
    for (int off = 1; off < 256; off <<= 1) {
        int x = (t >= off) ? sh[t - off] : 0;
        __syncthreads(); sh[t] += x; __syncthreads();
    }
    int run = sh[t] - my + bsum[blockIdx.x];
#pragma unroll
    for (int i = 0; i < 4; i++) { int idx = base + i; if (idx < NN) rowoff[idx] = run; run += v[i]; }
    if (blockIdx.x == 0 && t == 0) rowoff[NN] = ENN;
}

__global__ void csr_init_k(const int* __restrict__ rowoff, const float* __restrict__ dinv,
                           int* __restrict__ cursor, int* __restrict__ csrs, float* __restrict__ csrw) {
    int i = blockIdx.x * 256 + threadIdx.x;
    if (i < NN) {
        int p = rowoff[i];
        csrs[p] = i;
        float d = dinv[i];
        csrw[p] = d * d;         // self-loop weight
        cursor[i] = p + 1;
    }
}

__global__ void csr_place_k(const int* __restrict__ src, const int* __restrict__ dst,
                            const float* __restrict__ dinv, int* __restrict__ cursor,
                            int* __restrict__ csrs, float* __restrict__ csrw) {
    int e = blockIdx.x * 256 + threadIdx.x;
    if (e < EE) {
        int s = src[e], d = dst[e];
        int p = atomicAdd(&cursor[d], 1);
        csrs[p] = s;
        csrw[p] = dinv[s] * dinv[d];
    }
}

// ---------------- aggregate (pull-gather, no atomics) ----------------

__global__ void gather_k(const int* __restrict__ rowoff, const int* __restrict__ csrs,
                         const float* __restrict__ csrw, const float* __restrict__ h,
                         const float* __restrict__ bias, float* __restrict__ out) {
    int d = blockIdx.x;        // one block per dst node
    int c = threadIdx.x;       // 128 channels
    int beg = rowoff[d], end = rowoff[d + 1];
    float acc = 0.f;
    for (int e = beg; e < end; ++e) {
        int s = csrs[e];
        float w = csrw[e];
        acc += w * h[(size_t)s * DH + c];
    }
    out[(size_t)d * DH + c] = acc + bias[c];
}

// ---------------- batch norm ----------------

__global__ void bn_stats_k(const float* __restrict__ x, float* __restrict__ stats) {
    int c = threadIdx.x;   // 128
    int r0 = blockIdx.x * 512;
    int rend = r0 + 512; if (rend > NN) rend = NN;
    float s = 0.f, s2 = 0.f;
    for (int r = r0; r < rend; ++r) {
        float v = x[(size_t)r * DH + c];
        s += v; s2 += v * v;
    }
    atomicAdd(&stats[c], s);
    atomicAdd(&stats[DH + c], s2);
}

__global__ void bn_prelu_k(float* __restrict__ x, const float* __restrict__ stats,
                           const float* __restrict__ g, const float* __restrict__ be,
                           const float* __restrict__ a) {
    size_t i = (size_t)blockIdx.x * 256 + threadIdx.x;
    if (i < (size_t)NN * DH) {
        int c = (int)(i & (DH - 1));
        float mu = stats[c] * (1.0f / NN);
        float var = stats[DH + c] * (1.0f / NN) - mu * mu;
        float sc = rsqrtf(var + BN_EPS_C) * g[c];
        float v = (x[i] - mu) * sc + be[c];
        float alpha = a[0];
        x[i] = v >= 0.f ? v : alpha * v;
    }
}

// ---------------- fp32 tiled GEMM: C[nrows,M] = A[nrows,K] @ W[K,M] ----------------
// BM*M == 256*TM*TN, 256 threads, KC=16

template <int K, int M, int BM, int TM, int TN, bool BIAS, bool PRELU>
__global__ void gemm_k(const float* __restrict__ A, const float* __restrict__ W,
                       float* __restrict__ C, int nrows,
                       const float* __restrict__ bias, const float* __restrict__ aptr) {
    constexpr int KC = 16;
    __shared__ __align__(16) float sA[BM * KC];
    __shared__ __align__(16) float sW[KC * M];
    const int tid = threadIdx.x;
    const int row0 = blockIdx.x * BM;
    constexpr int CG = M / TN;          // column groups (=32 for our configs)
    const int tc = tid % CG;
    const int tr = tid / CG;            // 0..7
    const int r0 = tr * TM;
    const int c0 = tc * TN;

    float acc[TM][TN];
#pragma unroll
    for (int i = 0; i < TM; i++)
#pragma unroll
        for (int j = 0; j < TN; j++) acc[i][j] = 0.f;

    for (int k0 = 0; k0 < K; k0 += KC) {
        // stage A tile: BM x KC
        if (tid < BM * 4) {
            int r = tid >> 2, part = tid & 3;
            int grow = row0 + r;
            float4 v;
            if (grow < nrows) v = *(const float4*)&A[(size_t)grow * K + k0 + part * 4];
            else v = make_float4(0.f, 0.f, 0.f, 0.f);
            *(float4*)&sA[r * KC + part * 4] = v;
        }
        // stage W tile: KC x M
        for (int i = tid; i < KC * (M / 4); i += 256) {
            int kr = i / (M / 4), cg = i % (M / 4);
            *(float4*)&sW[kr * M + cg * 4] = *(const float4*)&W[(size_t)(k0 + kr) * M + cg * 4];
        }
        __syncthreads();
#pragma unroll
        for (int kk = 0; kk < KC; ++kk) {
            float a[TM];
#pragma unroll
            for (int i = 0; i < TM; i++) a[i] = sA[(r0 + i) * KC + kk];
            float w[TN];
#pragma unroll
            for (int j = 0; j < TN; j++) w[j] = sW[kk * M + c0 + j];
#pragma unroll
            for (int i = 0; i < TM; i++)
#pragma unroll
                for (int j = 0; j < TN; j++) acc[i][j] += a[i] * w[j];
        }
        __syncthreads();
    }

    float alpha = PRELU ? aptr[0] : 0.f;
#pragma unroll
    for (int i = 0; i < TM; i++) {
        int grow = row0 + r0 + i;
        if (grow < nrows) {
#pragma unroll
            for (int j = 0; j < TN; j++) {
                float v = acc[i][j];
                if (BIAS) v += bias[c0 + j];
                if (PRELU) v = v >= 0.f ? v : alpha * v;
                C[(size_t)grow * M + c0 + j] = v;
            }
        }
    }
}

// ---------------- loss ----------------

__global__ void loss_partial_k(const float* __restrict__ v1p, const float* __restrict__ v2t,
                               const float* __restrict__ v2p, const float* __restrict__ v1t,
                               float* __restrict__ partials) {
    __shared__ float shw[4];
    int t = threadIdx.x;
    int lane = t & 63, wv = t >> 6;
    float wsum = 0.f;
    for (int it = 0; it < 8; ++it) {
        int r = blockIdx.x * 32 + wv * 8 + it;
        if (r < NN) {
            const float* A = v1p + (size_t)r * DH;
            const float* B = v2t + (size_t)r * DH;
            const float* Cc = v2p + (size_t)r * DH;
            const float* D = v1t + (size_t)r * DH;
            float a0 = A[lane], a1 = A[lane + 64];
            float b0 = B[lane], b1 = B[lane + 64];
            float c0 = Cc[lane], c1 = Cc[lane + 64];
            float d0 = D[lane], d1 = D[lane + 64];
            float dot1 = a0 * b0 + a1 * b1;
            float na = a0 * a0 + a1 * a1, nb = b0 * b0 + b1 * b1;
            float dot2 = c0 * d0 + c1 * d1;
            float nc = c0 * c0 + c1 * c1, nd = d0 * d0 + d1 * d1;
            for (int off = 32; off > 0; off >>= 1) {
                dot1 += __shfl_down(dot1, off);
                na   += __shfl_down(na, off);
                nb   += __shfl_down(nb, off);
                dot2 += __shfl_down(dot2, off);
                nc   += __shfl_down(nc, off);
                nd   += __shfl_down(nd, off);
            }
            if (lane == 0) {
                float den1 = fmaxf(sqrtf(na), 1e-12f) * fmaxf(sqrtf(nb), 1e-12f);
                float den2 = fmaxf(sqrtf(nc), 1e-12f) * fmaxf(sqrtf(nd), 1e-12f);
                wsum += 4.f - 2.f * dot1 / den1 - 2.f * dot2 / den2;
            }
        }
    }
    if (lane == 0) shw[wv] = wsum;
    __syncthreads();
    if (t == 0) partials[blockIdx.x] = shw[0] + shw[1] + shw[2] + shw[3];
}

__global__ void loss_final_k(const float* __restrict__ partials, int n, float* __restrict__ out) {
    __shared__ float sh[256];
    int t = threadIdx.x;
    float s = 0.f;
    for (int i = t; i < n; i += 256) s += partials[i];
    sh[t] = s; __syncthreads();
    for (int off = 128; off > 0; off >>= 1) { if (t < off) sh[t] += sh[t + off]; __syncthreads(); }
    if (t == 0) out[0] = sh[0] / (float)NN;
}

// ---------------- host ----------------

extern "C" void kernel_launch(void* const* d_in, const int* in_sizes, int n_in,
                              void* d_out, int out_size, void* d_ws, size_t ws_size,
                              hipStream_t stream) {
    const float* x1 = (const float*)d_in[0];
    const float* x2 = (const float*)d_in[1];
    const int* ei1 = (const int*)d_in[2];
    const int* ei2 = (const int*)d_in[3];
    // student params 4..13, teacher 14..23
    const float* sp[10]; for (int i = 0; i < 10; i++) sp[i] = (const float*)d_in[4 + i];
    const float* tp[10]; for (int i = 0; i < 10; i++) tp[i] = (const float*)d_in[14 + i];
    const float* pW1 = (const float*)d_in[24];
    const float* pb1 = (const float*)d_in[25];
    const float* pa  = (const float*)d_in[26];
    const float* pW2 = (const float*)d_in[27];
    const float* pb2 = (const float*)d_in[28];

    float* out = (float*)d_out;
    float* v1s = out;
    float* v2s = out + (size_t)NN * DH;
    float* lossp = out + (size_t)2 * NN * DH;

    char* p = (char*)d_ws;
    auto alloc = [&](size_t bytes) { char* r = p; p += (bytes + 255) & ~(size_t)255; return r; };
    int*   deg1   = (int*)alloc(NN * 4);
    int*   deg2   = (int*)alloc(NN * 4);
    float* dinv1  = (float*)alloc(NN * 4);
    float* dinv2  = (float*)alloc(NN * 4);
    int*   ro1    = (int*)alloc((NN + 1) * 4);
    int*   ro2    = (int*)alloc((NN + 1) * 4);
    int*   cursor = (int*)alloc(NN * 4);
    int*   bsum   = (int*)alloc(128 * 4);
    int*   csrs1  = (int*)alloc((size_t)ENN * 4);
    float* csrw1  = (float*)alloc((size_t)ENN * 4);
    int*   csrs2  = (int*)alloc((size_t)ENN * 4);
    float* csrw2  = (float*)alloc((size_t)ENN * 4);
    float* t0     = (float*)alloc((size_t)NN * DH * 4);   // also predictor hidden chunk (25000*512*4 == NN*DH*4)
    float* t1     = (float*)alloc((size_t)NN * DH * 4);
    float* v1t    = (float*)alloc((size_t)NN * DH * 4);
    float* v2t    = (float*)alloc((size_t)NN * DH * 4);
    float* v1p    = (float*)alloc((size_t)NN * DH * 4);
    float* v2p    = (float*)alloc((size_t)NN * DH * 4);
    float* stats  = (float*)alloc(8 * 256 * 4);
    float* partials = (float*)alloc(4096 * 4);

    const int GN256 = (NN + 255) / 256;
    const int GE256 = (EE + 255) / 256;
    const int NB_SCAN = (NN + 1023) / 1024;  // 98

    hipMemsetAsync(stats, 0, 8 * 256 * 4, stream);

    // graph build
    init_deg_k<<<GN256, 256, 0, stream>>>(deg1, deg2);
    count_deg_k<<<GE256, 256, 0, stream>>>(ei1 + EE, deg1);
    count_deg_k<<<GE256, 256, 0, stream>>>(ei2 + EE, deg2);
    dinv_k<<<GN256, 256, 0, stream>>>(deg1, dinv1);
    dinv_k<<<GN256, 256, 0, stream>>>(deg2, dinv2);

    scan1_k<<<NB_SCAN, 256, 0, stream>>>(deg1, bsum);
    scan2_k<<<1, 128, 0, stream>>>(bsum, NB_SCAN);
    scan3_k<<<NB_SCAN, 256, 0, stream>>>(deg1, bsum, ro1);
    csr_init_k<<<GN256, 256, 0, stream>>>(ro1, dinv1, cursor, csrs1, csrw1);
    csr_place_k<<<GE256, 256, 0, stream>>>(ei1, ei1 + EE, dinv1, cursor, csrs1, csrw1);

    scan1_k<<<NB_SCAN, 256, 0, stream>>>(deg2, bsum);
    scan2_k<<<1, 128, 0, stream>>>(bsum, NB_SCAN);
    scan3_k<<<NB_SCAN, 256, 0, stream>>>(deg2, bsum, ro2);
    csr_init_k<<<GN256, 256, 0, stream>>>(ro2, dinv2, cursor, csrs2, csrw2);
    csr_place_k<<<GE256, 256, 0, stream>>>(ei2, ei2 + EE, dinv2, cursor, csrs2, csrw2);

    const int GBN = (NN + 511) / 512;
    const int GEL = (NN * DH + 255) / 256;

    auto encoder = [&](const float* x, const float* const* pr,
                       const int* ro, const int* csrs, const float* csrw,
                       float* outbuf, int sb) {
        // pr: W1 b1 g1 be1 a1 W2 b2 g2 be2 a2
        gemm_k<DIN, DH, 64, 8, 4, false, false><<<(NN + 63) / 64, 256, 0, stream>>>(
            x, pr[0], t0, NN, nullptr, nullptr);
        gather_k<<<NN, DH, 0, stream>>>(ro, csrs, csrw, t0, pr[1], t1);
        bn_stats_k<<<GBN, DH, 0, stream>>>(t1, stats + sb * 256);
        bn_prelu_k<<<GEL, 256, 0, stream>>>(t1, stats + sb * 256, pr[2], pr[3], pr[4]);
        gemm_k<DH, DH, 64, 8, 4, false, false><<<(NN + 63) / 64, 256, 0, stream>>>(
            t1, pr[5], t0, NN, nullptr, nullptr);
        gather_k<<<NN, DH, 0, stream>>>(ro, csrs, csrw, t0, pr[6], outbuf);
        bn_stats_k<<<GBN, DH, 0, stream>>>(outbuf, stats + (sb + 1) * 256);
        bn_prelu_k<<<GEL, 256, 0, stream>>>(outbuf, stats + (sb + 1) * 256, pr[7], pr[8], pr[9]);
    };

    encoder(x1, sp, ro1, csrs1, csrw1, v1s, 0);
    encoder(x2, sp, ro2, csrs2, csrw2, v2s, 2);
    encoder(x1, tp, ro1, csrs1, csrw1, v1t, 4);
    encoder(x2, tp, ro2, csrs2, csrw2, v2t, 6);

    auto predictor = [&](const float* vin, float* vout) {
        for (int c = 0; c < 4; c++) {
            int off = c * 25000, nc = 25000;
            gemm_k<DH, PH, 32, 4, 16, true, true><<<(nc + 31) / 32, 256, 0, stream>>>(
                vin + (size_t)off * DH, pW1, t0, nc, pb1, pa);
            gemm_k<PH, DH, 64, 8, 4, true, false><<<(nc + 63) / 64, 256, 0, stream>>>(
                t0, pW2, vout + (size_t)off * DH, nc, pb2, nullptr);
        }
    };
    predictor(v1s, v1p);
    predictor(v2s, v2p);

    const int GL = (NN + 31) / 32;  // 3125
    loss_partial_k<<<GL, 256, 0, stream>>>(v1p, v2t, v2p, v1t, partials);
    loss_final_k<<<1, 256, 0, stream>>>(partials, GL, lossp);
}

// Round 2
// 3993.913 us; speedup vs baseline: 1.7368x; 1.7368x over previous
//
#include <hip/hip_runtime.h>

#define NN 100000
#define EE 1600000
#define ENN (EE + NN)
#define DIN 256
#define DH 128
#define PH 512

static constexpr float BN_EPS_C = 1e-5f;

typedef __bf16 bf16_t;
typedef bf16_t bf16x8 __attribute__((ext_vector_type(8)));
typedef float floatx4 __attribute__((ext_vector_type(4)));

// ---------------- graph build ----------------

__global__ void init_deg_k(int* __restrict__ deg1, int* __restrict__ deg2) {
    int i = blockIdx.x * 256 + threadIdx.x;
    if (i < NN) { deg1[i] = 1; deg2[i] = 1; }  // self-loop counted here
}

__global__ void count_deg_k(const int* __restrict__ dst, int* __restrict__ deg) {
    int e = blockIdx.x * 256 + threadIdx.x;
    if (e < EE) atomicAdd(&deg[dst[e]], 1);
}

__global__ void dinv_k(const int* __restrict__ deg, float* __restrict__ dinv) {
    int i = blockIdx.x * 256 + threadIdx.x;
    if (i < NN) dinv[i] = rsqrtf((float)deg[i]);
}

__global__ void scan1_k(const int* __restrict__ deg, int* __restrict__ bsum) {
    __shared__ int sh[256];
    int t = threadIdx.x;
    int base = blockIdx.x * 1024 + t * 4;
    int s = 0;
#pragma unroll
    for (int i = 0; i < 4; i++) { int idx = base + i; if (idx < NN) s += deg[idx]; }
    sh[t] = s; __syncthreads();
    for (int off = 128; off > 0; off >>= 1) { if (t < off) sh[t] += sh[t + off]; __syncthreads(); }
    if (t == 0) bsum[blockIdx.x] = sh[0];
}

__global__ void scan2_k(int* __restrict__ bsum, int nb) {
    __shared__ int sh[128];
    int t = threadIdx.x;
    int my = (t < nb) ? bsum[t] : 0;
    sh[t] = my; __syncthreads();
    for (int off = 1; off < 128; off <<= 1) {
        int v = (t >= off) ? sh[t - off] : 0;
        __syncthreads(); sh[t] += v; __syncthreads();
    }
    if (t < nb) bsum[t] = sh[t] - my;  // exclusive
}

__global__ void scan3_k(const int* __restrict__ deg, const int* __restrict__ bsum,
                        int* __restrict__ rowoff) {
    __shared__ int sh[256];
    int t = threadIdx.x;
    int base = blockIdx.x * 1024 + t * 4;
    int v[4]; int s = 0;
#pragma unroll
    for (int i = 0; i < 4; i++) { int idx = base + i; v[i] = (idx < NN) ? deg[idx] : 0; s += v[i]; }
    int my = s;
    sh[t] = s; __syncthreads();
    for (int off = 1; off < 256; off <<= 1) {
        int x = (t >= off) ? sh[t - off] : 0;
        __syncthreads(); sh[t] += x; __syncthreads();
    }
    int run = sh[t] - my + bsum[blockIdx.x];
#pragma unroll
    for (int i = 0; i < 4; i++) { int idx = base + i; if (idx < NN) rowoff[idx] = run; run += v[i]; }
    if (blockIdx.x == 0 && t == 0) rowoff[NN] = ENN;
}

__global__ void csr_init_k(const int* __restrict__ rowoff, const float* __restrict__ dinv,
                           int* __restrict__ cursor, int* __restrict__ csrs, float* __restrict__ csrw) {
    int i = blockIdx.x * 256 + threadIdx.x;
    if (i < NN) {
        int p = rowoff[i];
        csrs[p] = i;
        float d = dinv[i];
        csrw[p] = d * d;         // self-loop weight
        cursor[i] = p + 1;
    }
}

__global__ void csr_place_k(const int* __restrict__ src, const int* __restrict__ dst,
                            const float* __restrict__ dinv, int* __restrict__ cursor,
                            int* __restrict__ csrs, float* __restrict__ csrw) {
    int e = blockIdx.x * 256 + threadIdx.x;
    if (e < EE) {
        int s = src[e], d = dst[e];
        int p = atomicAdd(&cursor[d], 1);
        csrs[p] = s;
        csrw[p] = dinv[s] * dinv[d];
    }
}

// ---------------- aggregate (pull-gather, no atomics) ----------------

__global__ void gather_k(const int* __restrict__ rowoff, const int* __restrict__ csrs,
                         const float* __restrict__ csrw, const float* __restrict__ h,
                         const float* __restrict__ bias, float* __restrict__ out) {
    int d = blockIdx.x;        // one block per dst node
    int c = threadIdx.x;       // 128 channels
    int beg = rowoff[d], end = rowoff[d + 1];
    float acc = 0.f;
    for (int e = beg; e < end; ++e) {
        int s = csrs[e];
        float w = csrw[e];
        acc += w * h[(size_t)s * DH + c];
    }
    out[(size_t)d * DH + c] = acc + bias[c];
}

// ---------------- batch norm ----------------

__global__ void bn_stats_k(const float* __restrict__ x, float* __restrict__ stats) {
    int c = threadIdx.x;   // 128
    int r0 = blockIdx.x * 512;
    int rend = r0 + 512; if (rend > NN) rend = NN;
    float s = 0.f, s2 = 0.f;
    for (int r = r0; r < rend; ++r) {
        float v = x[(size_t)r * DH + c];
        s += v; s2 += v * v;
    }
    atomicAdd(&stats[c], s);
    atomicAdd(&stats[DH + c], s2);
}

__global__ void bn_prelu_k(float* __restrict__ x, const float* __restrict__ stats,
                           const float* __restrict__ g, const float* __restrict__ be,
                           const float* __restrict__ a) {
    size_t i = (size_t)blockIdx.x * 256 + threadIdx.x;
    if (i < (size_t)NN * DH) {
        int c = (int)(i & (DH - 1));
        float mu = stats[c] * (1.0f / NN);
        float var = stats[DH + c] * (1.0f / NN) - mu * mu;
        float sc = rsqrtf(var + BN_EPS_C) * g[c];
        float v = (x[i] - mu) * sc + be[c];
        float alpha = a[0];
        x[i] = v >= 0.f ? v : alpha * v;
    }
}

// ---------------- weight transpose + bf16 convert: Wt[m][k] = W[k][m] ----------------

__global__ void wt_k(const float* __restrict__ W, bf16_t* __restrict__ Wt, int K, int M) {
    int i = blockIdx.x * 256 + threadIdx.x;
    if (i < K * M) {
        int k = i / M, m = i - k * M;
        Wt[(size_t)m * K + k] = (bf16_t)W[i];
    }
}

// ---------------- bf16 MFMA GEMM: C[nrows,M] = A[nrows,K] @ Wt^T ----------------
// Wt is [M][K] bf16 (pre-transposed weights). A is fp32, converted in staging.
// 128x128 block tile, 256 threads = 4 waves (2x2), each wave 64x64 via 4x4
// frags of v_mfma_f32_16x16x32_bf16. LDS rows padded +8 bf16 for bank spread.

#define LDT 40

template <int K, bool BIAS, bool PRELU>
__global__ __launch_bounds__(256) void mgemm_k(
    const float* __restrict__ A, const bf16_t* __restrict__ Wt,
    float* __restrict__ C, int nrows, int M,
    const float* __restrict__ bias, const float* __restrict__ prelu_a)
{
    __shared__ __align__(16) bf16_t sA[128 * LDT];
    __shared__ __align__(16) bf16_t sB[128 * LDT];
    const int tid = threadIdx.x;
    const int row0 = blockIdx.x * 128;
    const int col0 = blockIdx.y * 128;
    const int lane = tid & 63, quad = lane >> 4, l15 = lane & 15;
    const int wv = tid >> 6, wrow = wv >> 1, wcol = wv & 1;

    const int sr = tid >> 1;          // staging row 0..127
    const int sh = (tid & 1) * 16;    // staging k sub-offset (elements)

    floatx4 acc[4][4] = {};

    const int arow = row0 + sr;
    const bool arow_ok = arow < nrows;
    const float*  ag = A  + (size_t)arow * K + sh;
    const bf16_t* bg = Wt + (size_t)(col0 + sr) * K + sh;

    for (int k0 = 0; k0 < K; k0 += 32) {
        __syncthreads();
        // stage A tile (fp32 -> bf16)
        float4 f0, f1, f2, f3;
        if (arow_ok) {
            const float4* p4 = (const float4*)(ag + k0);
            f0 = p4[0]; f1 = p4[1]; f2 = p4[2]; f3 = p4[3];
        } else {
            f0 = f1 = f2 = f3 = make_float4(0.f, 0.f, 0.f, 0.f);
        }
        bf16x8 u0 = {(bf16_t)f0.x, (bf16_t)f0.y, (bf16_t)f0.z, (bf16_t)f0.w,
                     (bf16_t)f1.x, (bf16_t)f1.y, (bf16_t)f1.z, (bf16_t)f1.w};
        bf16x8 u1 = {(bf16_t)f2.x, (bf16_t)f2.y, (bf16_t)f2.z, (bf16_t)f2.w,
                     (bf16_t)f3.x, (bf16_t)f3.y, (bf16_t)f3.z, (bf16_t)f3.w};
        *(bf16x8*)&sA[sr * LDT + sh]     = u0;
        *(bf16x8*)&sA[sr * LDT + sh + 8] = u1;
        // stage B tile (already bf16, [n][k] rows)
        const int4* wp = (const int4*)(bg + k0);
        int4 w0 = wp[0], w1 = wp[1];
        *(int4*)&sB[sr * LDT + sh]     = w0;
        *(int4*)&sB[sr * LDT + sh + 8] = w1;
        __syncthreads();

        bf16x8 af[4], bf[4];
#pragma unroll
        for (int r = 0; r < 4; r++)
            af[r] = *(const bf16x8*)&sA[(wrow * 64 + r * 16 + l15) * LDT + quad * 8];
#pragma unroll
        for (int c = 0; c < 4; c++)
            bf[c] = *(const bf16x8*)&sB[(wcol * 64 + c * 16 + l15) * LDT + quad * 8];
#pragma unroll
        for (int r = 0; r < 4; r++)
#pragma unroll
            for (int c = 0; c < 4; c++)
                acc[r][c] = __builtin_amdgcn_mfma_f32_16x16x32_bf16(af[r], bf[c], acc[r][c], 0, 0, 0);
    }

    const float alpha = PRELU ? prelu_a[0] : 0.f;
#pragma unroll
    for (int r = 0; r < 4; r++) {
        const int rbase = wrow * 64 + r * 16 + quad * 4;
#pragma unroll
        for (int c = 0; c < 4; c++) {
            const int gcol = col0 + wcol * 64 + c * 16 + l15;
            const float bv = BIAS ? bias[gcol] : 0.f;
#pragma unroll
            for (int j = 0; j < 4; j++) {
                const int grow = row0 + rbase + j;
                if (grow < nrows) {
                    float v = acc[r][c][j] + bv;
                    if (PRELU) v = v >= 0.f ? v : alpha * v;
                    C[(size_t)grow * M + gcol] = v;
                }
            }
        }
    }
}

// ---------------- loss ----------------

__global__ void loss_partial_k(const float* __restrict__ v1p, const float* __restrict__ v2t,
                               const float* __restrict__ v2p, const float* __restrict__ v1t,
                               float* __restrict__ partials) {
    __shared__ float shw[4];
    int t = threadIdx.x;
    int lane = t & 63, wv = t >> 6;
    float wsum = 0.f;
    for (int it = 0; it < 8; ++it) {
        int r = blockIdx.x * 32 + wv * 8 + it;
        if (r < NN) {
            const float* A = v1p + (size_t)r * DH;
            const float* B = v2t + (size_t)r * DH;
            const float* Cc = v2p + (size_t)r * DH;
            const float* D = v1t + (size_t)r * DH;
            float a0 = A[lane], a1 = A[lane + 64];
            float b0 = B[lane], b1 = B[lane + 64];
            float c0 = Cc[lane], c1 = Cc[lane + 64];
            float d0 = D[lane], d1 = D[lane + 64];
            float dot1 = a0 * b0 + a1 * b1;
            float na = a0 * a0 + a1 * a1, nb = b0 * b0 + b1 * b1;
            float dot2 = c0 * d0 + c1 * d1;
            float nc = c0 * c0 + c1 * c1, nd = d0 * d0 + d1 * d1;
            for (int off = 32; off > 0; off >>= 1) {
                dot1 += __shfl_down(dot1, off);
                na   += __shfl_down(na, off);
                nb   += __shfl_down(nb, off);
                dot2 += __shfl_down(dot2, off);
                nc   += __shfl_down(nc, off);
                nd   += __shfl_down(nd, off);
            }
            if (lane == 0) {
                float den1 = fmaxf(sqrtf(na), 1e-12f) * fmaxf(sqrtf(nb), 1e-12f);
                float den2 = fmaxf(sqrtf(nc), 1e-12f) * fmaxf(sqrtf(nd), 1e-12f);
                wsum += 4.f - 2.f * dot1 / den1 - 2.f * dot2 / den2;
            }
        }
    }
    if (lane == 0) shw[wv] = wsum;
    __syncthreads();
    if (t == 0) partials[blockIdx.x] = shw[0] + shw[1] + shw[2] + shw[3];
}

__global__ void loss_final_k(const float* __restrict__ partials, int n, float* __restrict__ out) {
    __shared__ float sh[256];
    int t = threadIdx.x;
    float s = 0.f;
    for (int i = t; i < n; i += 256) s += partials[i];
    sh[t] = s; __syncthreads();
    for (int off = 128; off > 0; off >>= 1) { if (t < off) sh[t] += sh[t + off]; __syncthreads(); }
    if (t == 0) out[0] = sh[0] / (float)NN;
}

// ---------------- host ----------------

extern "C" void kernel_launch(void* const* d_in, const int* in_sizes, int n_in,
                              void* d_out, int out_size, void* d_ws, size_t ws_size,
                              hipStream_t stream) {
    const float* x1 = (const float*)d_in[0];
    const float* x2 = (const float*)d_in[1];
    const int* ei1 = (const int*)d_in[2];
    const int* ei2 = (const int*)d_in[3];
    const float* sp[10]; for (int i = 0; i < 10; i++) sp[i] = (const float*)d_in[4 + i];
    const float* tp[10]; for (int i = 0; i < 10; i++) tp[i] = (const float*)d_in[14 + i];
    const float* pW1 = (const float*)d_in[24];
    const float* pb1 = (const float*)d_in[25];
    const float* pa  = (const float*)d_in[26];
    const float* pW2 = (const float*)d_in[27];
    const float* pb2 = (const float*)d_in[28];

    float* out = (float*)d_out;
    float* v1s = out;
    float* v2s = out + (size_t)NN * DH;
    float* lossp = out + (size_t)2 * NN * DH;

    char* p = (char*)d_ws;
    auto alloc = [&](size_t bytes) { char* r = p; p += (bytes + 255) & ~(size_t)255; return r; };
    int*   deg1   = (int*)alloc(NN * 4);
    int*   deg2   = (int*)alloc(NN * 4);
    float* dinv1  = (float*)alloc(NN * 4);
    float* dinv2  = (float*)alloc(NN * 4);
    int*   ro1    = (int*)alloc((NN + 1) * 4);
    int*   ro2    = (int*)alloc((NN + 1) * 4);
    int*   cursor = (int*)alloc(NN * 4);
    int*   bsum   = (int*)alloc(128 * 4);
    int*   csrs1  = (int*)alloc((size_t)ENN * 4);
    float* csrw1  = (float*)alloc((size_t)ENN * 4);
    int*   csrs2  = (int*)alloc((size_t)ENN * 4);
    float* csrw2  = (float*)alloc((size_t)ENN * 4);
    float* t0     = (float*)alloc((size_t)NN * DH * 4);   // also predictor hidden chunk
    float* t1     = (float*)alloc((size_t)NN * DH * 4);
    float* v1t    = (float*)alloc((size_t)NN * DH * 4);
    float* v2t    = (float*)alloc((size_t)NN * DH * 4);
    float* v1p    = (float*)alloc((size_t)NN * DH * 4);
    float* v2p    = (float*)alloc((size_t)NN * DH * 4);
    float* stats  = (float*)alloc(8 * 256 * 4);
    float* partials = (float*)alloc(4096 * 4);
    // bf16 transposed weights
    bf16_t* sW1t = (bf16_t*)alloc((size_t)DIN * DH * 2);
    bf16_t* sW2t = (bf16_t*)alloc((size_t)DH * DH * 2);
    bf16_t* tW1t = (bf16_t*)alloc((size_t)DIN * DH * 2);
    bf16_t* tW2t = (bf16_t*)alloc((size_t)DH * DH * 2);
    bf16_t* pW1t = (bf16_t*)alloc((size_t)DH * PH * 2);
    bf16_t* pW2t = (bf16_t*)alloc((size_t)PH * DH * 2);

    const int GN256 = (NN + 255) / 256;
    const int GE256 = (EE + 255) / 256;
    const int NB_SCAN = (NN + 1023) / 1024;

    hipMemsetAsync(stats, 0, 8 * 256 * 4, stream);

    // weight transposes (bf16)
    wt_k<<<(DIN * DH + 255) / 256, 256, 0, stream>>>(sp[0], sW1t, DIN, DH);
    wt_k<<<(DH * DH + 255) / 256, 256, 0, stream>>>(sp[5], sW2t, DH, DH);
    wt_k<<<(DIN * DH + 255) / 256, 256, 0, stream>>>(tp[0], tW1t, DIN, DH);
    wt_k<<<(DH * DH + 255) / 256, 256, 0, stream>>>(tp[5], tW2t, DH, DH);
    wt_k<<<(DH * PH + 255) / 256, 256, 0, stream>>>(pW1, pW1t, DH, PH);
    wt_k<<<(PH * DH + 255) / 256, 256, 0, stream>>>(pW2, pW2t, PH, DH);

    // graph build
    init_deg_k<<<GN256, 256, 0, stream>>>(deg1, deg2);
    count_deg_k<<<GE256, 256, 0, stream>>>(ei1 + EE, deg1);
    count_deg_k<<<GE256, 256, 0, stream>>>(ei2 + EE, deg2);
    dinv_k<<<GN256, 256, 0, stream>>>(deg1, dinv1);
    dinv_k<<<GN256, 256, 0, stream>>>(deg2, dinv2);

    scan1_k<<<NB_SCAN, 256, 0, stream>>>(deg1, bsum);
    scan2_k<<<1, 128, 0, stream>>>(bsum, NB_SCAN);
    scan3_k<<<NB_SCAN, 256, 0, stream>>>(deg1, bsum, ro1);
    csr_init_k<<<GN256, 256, 0, stream>>>(ro1, dinv1, cursor, csrs1, csrw1);
    csr_place_k<<<GE256, 256, 0, stream>>>(ei1, ei1 + EE, dinv1, cursor, csrs1, csrw1);

    scan1_k<<<NB_SCAN, 256, 0, stream>>>(deg2, bsum);
    scan2_k<<<1, 128, 0, stream>>>(bsum, NB_SCAN);
    scan3_k<<<NB_SCAN, 256, 0, stream>>>(deg2, bsum, ro2);
    csr_init_k<<<GN256, 256, 0, stream>>>(ro2, dinv2, cursor, csrs2, csrw2);
    csr_place_k<<<GE256, 256, 0, stream>>>(ei2, ei2 + EE, dinv2, cursor, csrs2, csrw2);

    const int GBN = (NN + 511) / 512;
    const int GEL = (NN * DH + 255) / 256;
    const int GMM = (NN + 127) / 128;  // 782

    auto encoder = [&](const float* x, const float* const* pr,
                       const bf16_t* W1t, const bf16_t* W2t,
                       const int* ro, const int* csrs, const float* csrw,
                       float* outbuf, int sb) {
        mgemm_k<DIN, false, false><<<dim3(GMM, 1), 256, 0, stream>>>(
            x, W1t, t0, NN, DH, nullptr, nullptr);
        gather_k<<<NN, DH, 0, stream>>>(ro, csrs, csrw, t0, pr[1], t1);
        bn_stats_k<<<GBN, DH, 0, stream>>>(t1, stats + sb * 256);
        bn_prelu_k<<<GEL, 256, 0, stream>>>(t1, stats + sb * 256, pr[2], pr[3], pr[4]);
        mgemm_k<DH, false, false><<<dim3(GMM, 1), 256, 0, stream>>>(
            t1, W2t, t0, NN, DH, nullptr, nullptr);
        gather_k<<<NN, DH, 0, stream>>>(ro, csrs, csrw, t0, pr[6], outbuf);
        bn_stats_k<<<GBN, DH, 0, stream>>>(outbuf, stats + (sb + 1) * 256);
        bn_prelu_k<<<GEL, 256, 0, stream>>>(outbuf, stats + (sb + 1) * 256, pr[7], pr[8], pr[9]);
    };

    encoder(x1, sp, sW1t, sW2t, ro1, csrs1, csrw1, v1s, 0);
    encoder(x2, sp, sW1t, sW2t, ro2, csrs2, csrw2, v2s, 2);
    encoder(x1, tp, tW1t, tW2t, ro1, csrs1, csrw1, v1t, 4);
    encoder(x2, tp, tW1t, tW2t, ro2, csrs2, csrw2, v2t, 6);

    auto predictor = [&](const float* vin, float* vout) {
        for (int c = 0; c < 4; c++) {
            int off = c * 25000, nc = 25000;
            mgemm_k<DH, true, true><<<dim3((nc + 127) / 128, PH / 128), 256, 0, stream>>>(
                vin + (size_t)off * DH, pW1t, t0, nc, PH, pb1, pa);
            mgemm_k<PH, true, false><<<dim3((nc + 127) / 128, 1), 256, 0, stream>>>(
                t0, pW2t, vout + (size_t)off * DH, nc, DH, pb2, nullptr);
        }
    };
    predictor(v1s, v1p);
    predictor(v2s, v2p);

    const int GL = (NN + 31) / 32;
    loss_partial_k<<<GL, 256, 0, stream>>>(v1p, v2t, v2p, v1t, partials);
    loss_final_k<<<1, 256, 0, stream>>>(partials, GL, lossp);
}

// Round 3
// 2615.780 us; speedup vs baseline: 2.6518x; 1.5269x over previous
//
#include <hip/hip_runtime.h>

#define NN 100000
#define EE 1600000
#define ENN (EE + NN)
#define DIN 256
#define DH 128
#define PH 512

static constexpr float BN_EPS_C = 1e-5f;

typedef __bf16 bf16_t;
typedef bf16_t bf16x8 __attribute__((ext_vector_type(8)));
typedef float floatx4 __attribute__((ext_vector_type(4)));

// ---------------- graph build ----------------

__global__ void init_deg_k(int* __restrict__ deg1, int* __restrict__ deg2) {
    int i = blockIdx.x * 256 + threadIdx.x;
    if (i < NN) { deg1[i] = 1; deg2[i] = 1; }
}

__global__ void count_deg_k(const int* __restrict__ dst, int* __restrict__ deg) {
    int e = blockIdx.x * 256 + threadIdx.x;
    if (e < EE) atomicAdd(&deg[dst[e]], 1);
}

__global__ void dinv_k(const int* __restrict__ deg, float* __restrict__ dinv) {
    int i = blockIdx.x * 256 + threadIdx.x;
    if (i < NN) dinv[i] = rsqrtf((float)deg[i]);
}

__global__ void scan1_k(const int* __restrict__ deg, int* __restrict__ bsum) {
    __shared__ int sh[256];
    int t = threadIdx.x;
    int base = blockIdx.x * 1024 + t * 4;
    int s = 0;
#pragma unroll
    for (int i = 0; i < 4; i++) { int idx = base + i; if (idx < NN) s += deg[idx]; }
    sh[t] = s; __syncthreads();
    for (int off = 128; off > 0; off >>= 1) { if (t < off) sh[t] += sh[t + off]; __syncthreads(); }
    if (t == 0) bsum[blockIdx.x] = sh[0];
}

__global__ void scan2_k(int* __restrict__ bsum, int nb) {
    __shared__ int sh[128];
    int t = threadIdx.x;
    int my = (t < nb) ? bsum[t] : 0;
    sh[t] = my; __syncthreads();
    for (int off = 1; off < 128; off <<= 1) {
        int v = (t >= off) ? sh[t - off] : 0;
        __syncthreads(); sh[t] += v; __syncthreads();
    }
    if (t < nb) bsum[t] = sh[t] - my;
}

__global__ void scan3_k(const int* __restrict__ deg, const int* __restrict__ bsum,
                        int* __restrict__ rowoff) {
    __shared__ int sh[256];
    int t = threadIdx.x;
    int base = blockIdx.x * 1024 + t * 4;
    int v[4]; int s = 0;
#pragma unroll
    for (int i = 0; i < 4; i++) { int idx = base + i; v[i] = (idx < NN) ? deg[idx] : 0; s += v[i]; }
    int my = s;
    sh[t] = s; __syncthreads();
    for (int off = 1; off < 256; off <<= 1) {
        int x = (t >= off) ? sh[t - off] : 0;
        __syncthreads(); sh[t] += x; __syncthreads();
    }
    int run = sh[t] - my + bsum[blockIdx.x];
#pragma unroll
    for (int i = 0; i < 4; i++) { int idx = base + i; if (idx < NN) rowoff[idx] = run; run += v[i]; }
    if (blockIdx.x == 0 && t == 0) rowoff[NN] = ENN;
}

__global__ void csr_init_k(const int* __restrict__ rowoff, const float* __restrict__ dinv,
                           int* __restrict__ cursor, int2* __restrict__ csre) {
    int i = blockIdx.x * 256 + threadIdx.x;
    if (i < NN) {
        int p = rowoff[i];
        float d = dinv[i];
        csre[p] = make_int2(i, __float_as_int(d * d));
        cursor[i] = p + 1;
    }
}

__global__ void csr_place_k(const int* __restrict__ src, const int* __restrict__ dst,
                            const float* __restrict__ dinv, int* __restrict__ cursor,
                            int2* __restrict__ csre) {
    int e = blockIdx.x * 256 + threadIdx.x;
    if (e < EE) {
        int s = src[e], d = dst[e];
        int p = atomicAdd(&cursor[d], 1);
        csre[p] = make_int2(s, __float_as_int(dinv[s] * dinv[d]));
    }
}

// ---------------- fused 256-ch gather (student||teacher), bf16 rows ----------------
// one wave per dst node; lane covers 4 channels (8 B bf16x4 load per edge)

__global__ __launch_bounds__(256) void gather256_k(
    const int* __restrict__ ro, const int2* __restrict__ csre,
    const bf16_t* __restrict__ h,
    const float* __restrict__ bs, const float* __restrict__ bt,
    float* __restrict__ out)
{
    int wv = threadIdx.x >> 6, lane = threadIdx.x & 63;
    int d = blockIdx.x * 4 + wv;
    if (d >= NN) return;
    int beg = ro[d], end = ro[d + 1];
    int c4 = lane * 4;
    float a0 = 0.f, a1 = 0.f, a2 = 0.f, a3 = 0.f;
    for (int e = beg; e < end; ++e) {
        int2 ew = csre[e];
        float w = __int_as_float(ew.y);
        uint2 pr = *(const uint2*)(h + (size_t)ew.x * 256 + c4);
        a0 += w * __uint_as_float(pr.x << 16);
        a1 += w * __uint_as_float(pr.x & 0xffff0000u);
        a2 += w * __uint_as_float(pr.y << 16);
        a3 += w * __uint_as_float(pr.y & 0xffff0000u);
    }
    float b0 = (c4 < 128) ? bs[c4]     : bt[c4 - 128];
    float b1 = (c4 < 128) ? bs[c4 + 1] : bt[c4 - 127];
    float b2 = (c4 < 128) ? bs[c4 + 2] : bt[c4 - 126];
    float b3 = (c4 < 128) ? bs[c4 + 3] : bt[c4 - 125];
    float4 r = make_float4(a0 + b0, a1 + b1, a2 + b2, a3 + b3);
    *(float4*)&out[(size_t)d * 256 + c4] = r;
}

// ---------------- batch norm (256-ch concatenated) ----------------

__global__ void bn_stats_cat_k(const float* __restrict__ x, float* __restrict__ stats) {
    int c = threadIdx.x;   // 256 channels
    int r0 = blockIdx.x * 512;
    int rend = r0 + 512; if (rend > NN) rend = NN;
    float s = 0.f, s2 = 0.f;
    for (int r = r0; r < rend; ++r) {
        float v = x[(size_t)r * 256 + c];
        s += v; s2 += v * v;
    }
    atomicAdd(&stats[c], s);
    atomicAdd(&stats[256 + c], s2);
}

// normalize+prelu -> bf16 256-ch buffer (mid-layer)
__global__ void bn_prelu_cat_k(const float* __restrict__ x, const float* __restrict__ stats,
                               const float* __restrict__ gs, const float* __restrict__ gt,
                               const float* __restrict__ bes, const float* __restrict__ bet,
                               const float* __restrict__ as_, const float* __restrict__ at_,
                               bf16_t* __restrict__ out) {
    size_t i = (size_t)blockIdx.x * 256 + threadIdx.x;
    if (i < (size_t)NN * 256) {
        int c = (int)(i & 255);
        float mu = stats[c] * (1.0f / NN);
        float var = stats[256 + c] * (1.0f / NN) - mu * mu;
        float g  = (c < 128) ? gs[c]  : gt[c - 128];
        float be = (c < 128) ? bes[c] : bet[c - 128];
        float al = (c < 128) ? as_[0] : at_[0];
        float sc = rsqrtf(var + BN_EPS_C) * g;
        float v = (x[i] - mu) * sc + be;
        v = v >= 0.f ? v : al * v;
        out[i] = (bf16_t)v;
    }
}

// final layer: student half -> fp32 d_out + bf16 copy; teacher half -> bf16
__global__ void bn_prelu_out_k(const float* __restrict__ x, const float* __restrict__ stats,
                               const float* __restrict__ gs, const float* __restrict__ gt,
                               const float* __restrict__ bes, const float* __restrict__ bet,
                               const float* __restrict__ as_, const float* __restrict__ at_,
                               float* __restrict__ outs, bf16_t* __restrict__ outsb,
                               bf16_t* __restrict__ outt) {
    size_t i = (size_t)blockIdx.x * 256 + threadIdx.x;
    if (i < (size_t)NN * 256) {
        int c = (int)(i & 255);
        size_t r = i >> 8;
        float mu = stats[c] * (1.0f / NN);
        float var = stats[256 + c] * (1.0f / NN) - mu * mu;
        float g  = (c < 128) ? gs[c]  : gt[c - 128];
        float be = (c < 128) ? bes[c] : bet[c - 128];
        float al = (c < 128) ? as_[0] : at_[0];
        float sc = rsqrtf(var + BN_EPS_C) * g;
        float v = (x[i] - mu) * sc + be;
        v = v >= 0.f ? v : al * v;
        if (c < 128) {
            outs[r * 128 + c] = v;
            outsb[r * 128 + c] = (bf16_t)v;
        } else {
            outt[r * 128 + (c - 128)] = (bf16_t)v;
        }
    }
}

// ---------------- weight transpose + bf16: Wt[m][k] = W[k][m] ----------------

__global__ void wt_k(const float* __restrict__ W, bf16_t* __restrict__ Wt, int K, int M) {
    int i = blockIdx.x * 256 + threadIdx.x;
    if (i < K * M) {
        int k = i / M, m = i - k * M;
        Wt[(size_t)m * K + k] = (bf16_t)W[i];
    }
}

// ---------------- bf16 MFMA GEMM ----------------
// C[nrows, Mlogical] = A[nrows,K] @ Wt^T; A fp32 or bf16 (lda stride), C fp32 or bf16 (ldc stride)

#define LDT 40

template <int K, typename AT, typename OT, bool BIAS, bool PRELU>
__global__ __launch_bounds__(256) void mgemm_k(
    const AT* __restrict__ A, int lda, const bf16_t* __restrict__ Wt,
    OT* __restrict__ C, int ldc, int nrows,
    const float* __restrict__ bias, const float* __restrict__ prelu_a)
{
    __shared__ __align__(16) bf16_t sA[128 * LDT];
    __shared__ __align__(16) bf16_t sB[128 * LDT];
    const int tid = threadIdx.x;
    const int row0 = blockIdx.x * 128;
    const int col0 = blockIdx.y * 128;
    const int lane = tid & 63, quad = lane >> 4, l15 = lane & 15;
    const int wv = tid >> 6, wrow = wv >> 1, wcol = wv & 1;

    const int sr = tid >> 1;          // staging row 0..127
    const int sh = (tid & 1) * 16;    // staging k sub-offset (elements)

    floatx4 acc[4][4] = {};

    const int arow = row0 + sr;
    const bool arow_ok = arow < nrows;
    const AT*     ag = A  + (size_t)arow * lda + sh;
    const bf16_t* bg = Wt + (size_t)(col0 + sr) * K + sh;

    for (int k0 = 0; k0 < K; k0 += 32) {
        __syncthreads();
        if constexpr (sizeof(AT) == 4) {
            float4 f0, f1, f2, f3;
            if (arow_ok) {
                const float4* p4 = (const float4*)(ag + k0);
                f0 = p4[0]; f1 = p4[1]; f2 = p4[2]; f3 = p4[3];
            } else {
                f0 = f1 = f2 = f3 = make_float4(0.f, 0.f, 0.f, 0.f);
            }
            bf16x8 u0 = {(bf16_t)f0.x, (bf16_t)f0.y, (bf16_t)f0.z, (bf16_t)f0.w,
                         (bf16_t)f1.x, (bf16_t)f1.y, (bf16_t)f1.z, (bf16_t)f1.w};
            bf16x8 u1 = {(bf16_t)f2.x, (bf16_t)f2.y, (bf16_t)f2.z, (bf16_t)f2.w,
                         (bf16_t)f3.x, (bf16_t)f3.y, (bf16_t)f3.z, (bf16_t)f3.w};
            *(bf16x8*)&sA[sr * LDT + sh]     = u0;
            *(bf16x8*)&sA[sr * LDT + sh + 8] = u1;
        } else {
            int4 w0, w1;
            if (arow_ok) {
                const int4* p4 = (const int4*)(ag + k0);
                w0 = p4[0]; w1 = p4[1];
            } else {
                w0 = make_int4(0, 0, 0, 0); w1 = make_int4(0, 0, 0, 0);
            }
            *(int4*)&sA[sr * LDT + sh]     = w0;
            *(int4*)&sA[sr * LDT + sh + 8] = w1;
        }
        {
            const int4* wp = (const int4*)(bg + k0);
            int4 w0 = wp[0], w1 = wp[1];
            *(int4*)&sB[sr * LDT + sh]     = w0;
            *(int4*)&sB[sr * LDT + sh + 8] = w1;
        }
        __syncthreads();

        bf16x8 af[4], bf[4];
#pragma unroll
        for (int r = 0; r < 4; r++)
            af[r] = *(const bf16x8*)&sA[(wrow * 64 + r * 16 + l15) * LDT + quad * 8];
#pragma unroll
        for (int c = 0; c < 4; c++)
            bf[c] = *(const bf16x8*)&sB[(wcol * 64 + c * 16 + l15) * LDT + quad * 8];
#pragma unroll
        for (int r = 0; r < 4; r++)
#pragma unroll
            for (int c = 0; c < 4; c++)
                acc[r][c] = __builtin_amdgcn_mfma_f32_16x16x32_bf16(af[r], bf[c], acc[r][c], 0, 0, 0);
    }

    const float alpha = PRELU ? prelu_a[0] : 0.f;
#pragma unroll
    for (int r = 0; r < 4; r++) {
        const int rbase = wrow * 64 + r * 16 + quad * 4;
#pragma unroll
        for (int c = 0; c < 4; c++) {
            const int gcol = col0 + wcol * 64 + c * 16 + l15;
            const float bv = BIAS ? bias[gcol] : 0.f;
#pragma unroll
            for (int j = 0; j < 4; j++) {
                const int grow = row0 + rbase + j;
                if (grow < nrows) {
                    float v = acc[r][c][j] + bv;
                    if (PRELU) v = v >= 0.f ? v : alpha * v;
                    C[(size_t)grow * ldc + gcol] = (OT)v;
                }
            }
        }
    }
}

// ---------------- loss (all bf16 inputs) ----------------

__global__ void loss_partial_k(const bf16_t* __restrict__ v1p, const bf16_t* __restrict__ v2t,
                               const bf16_t* __restrict__ v2p, const bf16_t* __restrict__ v1t,
                               float* __restrict__ partials) {
    __shared__ float shw[4];
    int t = threadIdx.x;
    int lane = t & 63, wv = t >> 6;
    float wsum = 0.f;
    for (int it = 0; it < 8; ++it) {
        int r = blockIdx.x * 32 + wv * 8 + it;
        if (r < NN) {
            const bf16_t* A = v1p + (size_t)r * DH;
            const bf16_t* B = v2t + (size_t)r * DH;
            const bf16_t* Cc = v2p + (size_t)r * DH;
            const bf16_t* D = v1t + (size_t)r * DH;
            float a0 = (float)A[lane], a1 = (float)A[lane + 64];
            float b0 = (float)B[lane], b1 = (float)B[lane + 64];
            float c0 = (float)Cc[lane], c1 = (float)Cc[lane + 64];
            float d0 = (float)D[lane], d1 = (float)D[lane + 64];
            float dot1 = a0 * b0 + a1 * b1;
            float na = a0 * a0 + a1 * a1, nb = b0 * b0 + b1 * b1;
            float dot2 = c0 * d0 + c1 * d1;
            float nc = c0 * c0 + c1 * c1, nd = d0 * d0 + d1 * d1;
            for (int off = 32; off > 0; off >>= 1) {
                dot1 += __shfl_down(dot1, off);
                na   += __shfl_down(na, off);
                nb   += __shfl_down(nb, off);
                dot2 += __shfl_down(dot2, off);
                nc   += __shfl_down(nc, off);
                nd   += __shfl_down(nd, off);
            }
            if (lane == 0) {
                float den1 = fmaxf(sqrtf(na), 1e-12f) * fmaxf(sqrtf(nb), 1e-12f);
                float den2 = fmaxf(sqrtf(nc), 1e-12f) * fmaxf(sqrtf(nd), 1e-12f);
                wsum += 4.f - 2.f * dot1 / den1 - 2.f * dot2 / den2;
            }
        }
    }
    if (lane == 0) shw[wv] = wsum;
    __syncthreads();
    if (t == 0) partials[blockIdx.x] = shw[0] + shw[1] + shw[2] + shw[3];
}

__global__ void loss_final_k(const float* __restrict__ partials, int n, float* __restrict__ out) {
    __shared__ float sh[256];
    int t = threadIdx.x;
    float s = 0.f;
    for (int i = t; i < n; i += 256) s += partials[i];
    sh[t] = s; __syncthreads();
    for (int off = 128; off > 0; off >>= 1) { if (t < off) sh[t] += sh[t + off]; __syncthreads(); }
    if (t == 0) out[0] = sh[0] / (float)NN;
}

// ---------------- host ----------------

extern "C" void kernel_launch(void* const* d_in, const int* in_sizes, int n_in,
                              void* d_out, int out_size, void* d_ws, size_t ws_size,
                              hipStream_t stream) {
    const float* x1 = (const float*)d_in[0];
    const float* x2 = (const float*)d_in[1];
    const int* ei1 = (const int*)d_in[2];
    const int* ei2 = (const int*)d_in[3];
    const float* sp[10]; for (int i = 0; i < 10; i++) sp[i] = (const float*)d_in[4 + i];
    const float* tp[10]; for (int i = 0; i < 10; i++) tp[i] = (const float*)d_in[14 + i];
    const float* pW1 = (const float*)d_in[24];
    const float* pb1 = (const float*)d_in[25];
    const float* pa  = (const float*)d_in[26];
    const float* pW2 = (const float*)d_in[27];
    const float* pb2 = (const float*)d_in[28];

    float* out = (float*)d_out;
    float* v1s = out;
    float* v2s = out + (size_t)NN * DH;
    float* lossp = out + (size_t)2 * NN * DH;

    char* p = (char*)d_ws;
    auto alloc = [&](size_t bytes) { char* r = p; p += (bytes + 255) & ~(size_t)255; return r; };
    int*   deg1   = (int*)alloc(NN * 4);
    int*   deg2   = (int*)alloc(NN * 4);
    float* dinv1  = (float*)alloc(NN * 4);
    float* dinv2  = (float*)alloc(NN * 4);
    int*   ro1    = (int*)alloc((NN + 1) * 4);
    int*   ro2    = (int*)alloc((NN + 1) * 4);
    int*   cursor = (int*)alloc(NN * 4);
    int*   bsum   = (int*)alloc(128 * 4);
    int2*  csre1  = (int2*)alloc((size_t)ENN * 8);
    int2*  csre2  = (int2*)alloc((size_t)ENN * 8);
    bf16_t* hcat  = (bf16_t*)alloc((size_t)NN * 256 * 2);  // GEMM out / normalized h1 (reused)
    bf16_t* h2    = (bf16_t*)alloc((size_t)NN * 256 * 2);  // layer-2 GEMM out
    float*  agg   = (float*)alloc((size_t)NN * 256 * 4);   // gather out; later predictor hidden (bf16)
    bf16_t* v1sb  = (bf16_t*)alloc((size_t)NN * DH * 2);
    bf16_t* v2sb  = (bf16_t*)alloc((size_t)NN * DH * 2);
    bf16_t* v1t   = (bf16_t*)alloc((size_t)NN * DH * 2);
    bf16_t* v2t   = (bf16_t*)alloc((size_t)NN * DH * 2);
    bf16_t* v1p   = (bf16_t*)alloc((size_t)NN * DH * 2);
    bf16_t* v2p   = (bf16_t*)alloc((size_t)NN * DH * 2);
    float* stats  = (float*)alloc(4 * 512 * 4);
    float* partials = (float*)alloc(4096 * 4);
    bf16_t* sW1t = (bf16_t*)alloc((size_t)DIN * DH * 2);
    bf16_t* sW2t = (bf16_t*)alloc((size_t)DH * DH * 2);
    bf16_t* tW1t = (bf16_t*)alloc((size_t)DIN * DH * 2);
    bf16_t* tW2t = (bf16_t*)alloc((size_t)DH * DH * 2);
    bf16_t* pW1t = (bf16_t*)alloc((size_t)DH * PH * 2);
    bf16_t* pW2t = (bf16_t*)alloc((size_t)PH * DH * 2);

    const int GN256 = (NN + 255) / 256;
    const int GE256 = (EE + 255) / 256;
    const int NB_SCAN = (NN + 1023) / 1024;
    const int GMM = (NN + 127) / 128;      // 782
    const int GG = (NN + 3) / 4;           // 25000
    const int GBN = (NN + 511) / 512;      // 196
    const int GEL = NN;                    // NN*256/256 blocks

    hipMemsetAsync(stats, 0, 4 * 512 * 4, stream);

    wt_k<<<(DIN * DH + 255) / 256, 256, 0, stream>>>(sp[0], sW1t, DIN, DH);
    wt_k<<<(DH * DH + 255) / 256, 256, 0, stream>>>(sp[5], sW2t, DH, DH);
    wt_k<<<(DIN * DH + 255) / 256, 256, 0, stream>>>(tp[0], tW1t, DIN, DH);
    wt_k<<<(DH * DH + 255) / 256, 256, 0, stream>>>(tp[5], tW2t, DH, DH);
    wt_k<<<(DH * PH + 255) / 256, 256, 0, stream>>>(pW1, pW1t, DH, PH);
    wt_k<<<(PH * DH + 255) / 256, 256, 0, stream>>>(pW2, pW2t, PH, DH);

    init_deg_k<<<GN256, 256, 0, stream>>>(deg1, deg2);
    count_deg_k<<<GE256, 256, 0, stream>>>(ei1 + EE, deg1);
    count_deg_k<<<GE256, 256, 0, stream>>>(ei2 + EE, deg2);
    dinv_k<<<GN256, 256, 0, stream>>>(deg1, dinv1);
    dinv_k<<<GN256, 256, 0, stream>>>(deg2, dinv2);

    scan1_k<<<NB_SCAN, 256, 0, stream>>>(deg1, bsum);
    scan2_k<<<1, 128, 0, stream>>>(bsum, NB_SCAN);
    scan3_k<<<NB_SCAN, 256, 0, stream>>>(deg1, bsum, ro1);
    csr_init_k<<<GN256, 256, 0, stream>>>(ro1, dinv1, cursor, csre1);
    csr_place_k<<<GE256, 256, 0, stream>>>(ei1, ei1 + EE, dinv1, cursor, csre1);

    scan1_k<<<NB_SCAN, 256, 0, stream>>>(deg2, bsum);
    scan2_k<<<1, 128, 0, stream>>>(bsum, NB_SCAN);
    scan3_k<<<NB_SCAN, 256, 0, stream>>>(deg2, bsum, ro2);
    csr_init_k<<<GN256, 256, 0, stream>>>(ro2, dinv2, cursor, csre2);
    csr_place_k<<<GE256, 256, 0, stream>>>(ei2, ei2 + EE, dinv2, cursor, csre2);

    // fused s||t encoder per view
    auto encoder = [&](const float* x, const int* ro, const int2* csre,
                       float* vs_out, bf16_t* vsb, bf16_t* vt, int set) {
        // layer 1: GEMMs into hcat halves
        mgemm_k<DIN, float, bf16_t, false, false><<<dim3(GMM, 1), 256, 0, stream>>>(
            x, DIN, sW1t, hcat, 256, NN, nullptr, nullptr);
        mgemm_k<DIN, float, bf16_t, false, false><<<dim3(GMM, 1), 256, 0, stream>>>(
            x, DIN, tW1t, hcat + 128, 256, NN, nullptr, nullptr);
        gather256_k<<<GG, 256, 0, stream>>>(ro, csre, hcat, sp[1], tp[1], agg);
        bn_stats_cat_k<<<GBN, 256, 0, stream>>>(agg, stats + set * 512);
        bn_prelu_cat_k<<<GEL, 256, 0, stream>>>(agg, stats + set * 512,
            sp[2], tp[2], sp[3], tp[3], sp[4], tp[4], hcat);
        // layer 2
        mgemm_k<DH, bf16_t, bf16_t, false, false><<<dim3(GMM, 1), 256, 0, stream>>>(
            hcat, 256, sW2t, h2, 256, NN, nullptr, nullptr);
        mgemm_k<DH, bf16_t, bf16_t, false, false><<<dim3(GMM, 1), 256, 0, stream>>>(
            hcat + 128, 256, tW2t, h2 + 128, 256, NN, nullptr, nullptr);
        gather256_k<<<GG, 256, 0, stream>>>(ro, csre, h2, sp[6], tp[6], agg);
        bn_stats_cat_k<<<GBN, 256, 0, stream>>>(agg, stats + (set + 1) * 512);
        bn_prelu_out_k<<<GEL, 256, 0, stream>>>(agg, stats + (set + 1) * 512,
            sp[7], tp[7], sp[8], tp[8], sp[9], tp[9], vs_out, vsb, vt);
    };

    encoder(x1, ro1, csre1, v1s, v1sb, v1t, 0);
    encoder(x2, ro2, csre2, v2s, v2sb, v2t, 2);

    // predictor (full N, hidden reuses agg as bf16 [N][512])
    bf16_t* hid = (bf16_t*)agg;
    auto predictor = [&](const bf16_t* vin, bf16_t* vout) {
        mgemm_k<DH, bf16_t, bf16_t, true, true><<<dim3(GMM, PH / 128), 256, 0, stream>>>(
            vin, DH, pW1t, hid, PH, NN, pb1, pa);
        mgemm_k<PH, bf16_t, bf16_t, true, false><<<dim3(GMM, 1), 256, 0, stream>>>(
            hid, PH, pW2t, vout, DH, NN, pb2, nullptr);
    };
    predictor(v1sb, v1p);
    predictor(v2sb, v2p);

    const int GL = (NN + 31) / 32;
    loss_partial_k<<<GL, 256, 0, stream>>>(v1p, v2t, v2p, v1t, partials);
    loss_final_k<<<1, 256, 0, stream>>>(partials, GL, lossp);
}